// Round 3
// baseline (251.382 us; speedup 1.0000x reference)
//
#include <hip/hip_runtime.h>
#include <hip/hip_bf16.h>

// Causal flash attention fwd. B=2,H=16,S=2048,D=128, fp32 io, bf16 MFMA.
// R6: BM=128 (2 MFMAs per K/V ds_read, R5's real win) WITHOUT R5's VGPR
// spill (R5: WRITE_SIZE +6MB scratch). Double-buffered LDS (64 KB) lets us
// stage tile kt+1 mid-iteration; K-staging right after softmax frees ka/kc
// before V-loads are issued -> ka/kc and vr never simultaneously live.
// One barrier per iteration. Swizzles, cvt_pk/exp2/defer-max from R4/R5.
constexpr int Bb = 2, Hh = 16, Ss = 2048, Dd = 128;
constexpr int BM = 128, BN = 64;
constexpr int NQT = Ss / BM;                       // 16
// 1/sqrt(128) * log2(e): scores in log2 units.
constexpr float SCALE = 0.088388347648318447f * 1.4426950408889634f;

typedef __attribute__((ext_vector_type(8))) short bf16x8;
typedef __attribute__((ext_vector_type(4))) float f32x4;
typedef __attribute__((ext_vector_type(4))) int int4v;

__device__ __forceinline__ unsigned cvtpk(float lo, float hi) {
  unsigned r;
  asm("v_cvt_pk_bf16_f32 %0, %1, %2" : "=v"(r) : "v"(lo), "v"(hi));
  return r;                                    // [15:0]=bf16(lo) [31:16]=bf16(hi), RNE
}
__device__ __forceinline__ float exp2hw(float x) {
  float r;
  asm("v_exp_f32 %0, %1" : "=v"(r) : "v"(x));  // hardware exp2
  return r;
}
__device__ __forceinline__ float fcomp(float4 f, int j) {   // j is unroll-constant
  return j == 0 ? f.x : (j == 1 ? f.y : (j == 2 ? f.z : f.w));
}

__global__ __launch_bounds__(256, 2)
void fa_fwd_kernel(const float* __restrict__ q, const float* __restrict__ k,
                   const float* __restrict__ v, float* __restrict__ out) {
  // K tile row-major bf16: row=256B (16x16B blocks), block b at b^(row&15)
  __shared__ __align__(16) char Klds[2][BN * 256];    // 2 x 16 KB
  // V tile transposed Vt[d][key]: row=128B (8x16B blocks), block b at b^((d^(d>>3))&7)
  __shared__ __align__(16) char Vlds[2][Dd * 128];    // 2 x 16 KB

  const int tid = threadIdx.x;
  const int wave = tid >> 6, lane = tid & 63, quad = lane >> 4, l16 = lane & 15;
  const int bid = blockIdx.x;
  const int bh = bid & 31;
  const int r2 = bid >> 5;
  // complementary pairing: blocks i and i+256 get qt summing to 15 ->
  // uniform per-CU work across the two dispatch rounds; heavies first.
  const int qt = (r2 < 8) ? (15 - r2) : (r2 - 8);

  const float* qb = q + (size_t)bh * Ss * Dd;
  const float* kb = k + (size_t)bh * Ss * Dd;
  const float* vb = v + (size_t)bh * Ss * Dd;

  // ---- Q fragments (scale*log2e folded), two halves.
  // qf[h][ks]: lane holds Q[qrow = qt*128 + h*64 + wave*16 + l16][d=32ks+8quad+j]
  bf16x8 qf[2][4];
  #pragma unroll
  for (int h = 0; h < 2; ++h) {
    const float* qr = qb + (size_t)(qt * BM + h * 64 + wave * 16 + l16) * Dd + quad * 8;
    #pragma unroll
    for (int ks = 0; ks < 4; ++ks) {
      float4 a = *(const float4*)(qr + ks * 32);
      float4 b = *(const float4*)(qr + ks * 32 + 4);
      int4v t;
      t[0] = (int)cvtpk(a.x * SCALE, a.y * SCALE);
      t[1] = (int)cvtpk(a.z * SCALE, a.w * SCALE);
      t[2] = (int)cvtpk(b.x * SCALE, b.y * SCALE);
      t[3] = (int)cvtpk(b.z * SCALE, b.w * SCALE);
      qf[h][ks] = __builtin_bit_cast(bf16x8, t);
    }
  }

  // ---- staging geometry (constant per thread)
  const int krow0 = tid >> 4;            // 0..15
  const int kblk  = tid & 15;            // block index = d/8
  const int kswz  = kblk ^ krow0;        // row&15 == krow0 for all i
  const int vkg = tid >> 5;              // 0..7  (keys vkg*8 .. +7)
  const int vdq = tid & 31;              // d0 = vdq*4

  float4 ka[4], kc[4];                   // K prefetch (live QK^T..stage_k only)
  float4 vr[8];                          // V prefetch (live PV..stage_v only)

  auto load_k = [&](int kt) {
    const float* Kg = kb + (size_t)(kt * BN) * Dd + kblk * 8;
    #pragma unroll
    for (int i = 0; i < 4; ++i) {
      ka[i] = *(const float4*)(Kg + (size_t)(krow0 + 16 * i) * Dd);
      kc[i] = *(const float4*)(Kg + (size_t)(krow0 + 16 * i) * Dd + 4);
    }
  };
  auto load_v = [&](int kt) {
    const float* Vg = vb + (size_t)(kt * BN + vkg * 8) * Dd + vdq * 4;
    #pragma unroll
    for (int r = 0; r < 8; ++r)
      vr[r] = *(const float4*)(Vg + (size_t)r * Dd);
  };

  auto stage_k = [&](char* Kb) {
    #pragma unroll
    for (int i = 0; i < 4; ++i) {
      int4v t;
      t[0] = (int)cvtpk(ka[i].x, ka[i].y);
      t[1] = (int)cvtpk(ka[i].z, ka[i].w);
      t[2] = (int)cvtpk(kc[i].x, kc[i].y);
      t[3] = (int)cvtpk(kc[i].z, kc[i].w);
      *(int4v*)(Kb + (krow0 + 16 * i) * 256 + kswz * 16) = t;
    }
  };
  auto stage_v = [&](char* Vb) {
    #pragma unroll
    for (int j = 0; j < 4; ++j) {
      int d = vdq * 4 + j;
      int f7 = (d ^ (d >> 3)) & 7;
      int4v t;
      t[0] = (int)cvtpk(fcomp(vr[0], j), fcomp(vr[1], j));
      t[1] = (int)cvtpk(fcomp(vr[2], j), fcomp(vr[3], j));
      t[2] = (int)cvtpk(fcomp(vr[4], j), fcomp(vr[5], j));
      t[3] = (int)cvtpk(fcomp(vr[6], j), fcomp(vr[7], j));
      *(int4v*)(Vb + d * 128 + (vkg ^ f7) * 16) = t;
    }
  };

  f32x4 o[2][8];
  #pragma unroll
  for (int h = 0; h < 2; ++h)
    #pragma unroll
    for (int i = 0; i < 8; ++i) o[h][i] = (f32x4)(0.0f);
  float mrow[2] = {-3.0e38f, -3.0e38f};
  float lrow[2] = {0.0f, 0.0f};          // per-lane PARTIAL sums

  load_k(0); load_v(0);
  stage_k(&Klds[0][0]); stage_v(&Vlds[0][0]);

  const int hi2 = quad >> 1;
  const int srcbase = (l16 + 32 * (quad & 1)) * 4;   // bpermute byte base
  const int w16l16 = wave * 16 + l16;
  const int nkt = 2 * qt + 2;

  for (int kt = 0; kt < nkt; ++kt) {
    __syncthreads();                     // buf[cur] staged; buf[cur^1] free
    const int cur = kt & 1;
    const char* Kc = &Klds[cur][0];
    const char* Vc = &Vlds[cur][0];
    const bool more = kt + 1 < nkt;
    if (more) load_k(kt + 1);            // issue K prefetch (latency under QK^T)

    // ---- S^T = K Q^T : acc[nt][h][r] = S[qrow=h*64+w*16+l16][key=kt*64+nt*16+quad*4+r]
    f32x4 acc[4][2];
    #pragma unroll
    for (int nt = 0; nt < 4; ++nt) { acc[nt][0] = (f32x4)(0.0f); acc[nt][1] = (f32x4)(0.0f); }
    __builtin_amdgcn_s_setprio(1);
    #pragma unroll
    for (int ks = 0; ks < 4; ++ks) {
      #pragma unroll
      for (int nt = 0; nt < 4; ++nt) {
        int row = nt * 16 + l16;
        int bswz = (ks * 4 + quad) ^ l16;
        bf16x8 kf = *(const bf16x8*)(Kc + row * 256 + bswz * 16);
        acc[nt][0] = __builtin_amdgcn_mfma_f32_16x16x32_bf16(kf, qf[0][ks], acc[nt][0], 0, 0, 0);
        acc[nt][1] = __builtin_amdgcn_mfma_f32_16x16x32_bf16(kf, qf[1][ks], acc[nt][1], 0, 0, 0);
      }
    }
    __builtin_amdgcn_s_setprio(0);

    // ---- causal mask. Diagonal tile for h=0 is kt==nkt-2, for h=1 kt==nkt-1.
    // On the final tile h=0 is fully masked -> handled by pf[0]=0 below.
    if (kt == nkt - 2) {
      #pragma unroll
      for (int nt = 0; nt < 4; ++nt)
        #pragma unroll
        for (int r = 0; r < 4; ++r)
          if (nt * 16 + quad * 4 + r > w16l16) acc[nt][0][r] = -1.0e30f;
    }
    if (kt == nkt - 1) {
      #pragma unroll
      for (int nt = 0; nt < 4; ++nt)
        #pragma unroll
        for (int r = 0; r < 4; ++r)
          if (nt * 16 + quad * 4 + r > w16l16) acc[nt][1][r] = -1.0e30f;
    }
    const bool doh0 = (kt != nkt - 1);

    // ---- online softmax per half (log2 domain) + P pack + bpermute transform
    bf16x8 pf[2][2];
    #pragma unroll
    for (int h = 0; h < 2; ++h) {
      bool act = (h == 1) || doh0;
      if (act) {
        float mx = acc[0][h][0];
        #pragma unroll
        for (int nt = 0; nt < 4; ++nt)
          #pragma unroll
          for (int r = 0; r < 4; ++r) mx = fmaxf(mx, acc[nt][h][r]);
        mx = fmaxf(mx, __shfl_xor(mx, 16, 64));
        mx = fmaxf(mx, __shfl_xor(mx, 32, 64));

        if (!__all(mx - mrow[h] <= 8.0f)) {       // defer-max, THR=8 (log2)
          float mn = fmaxf(mrow[h], mx);
          float alpha = exp2hw(mrow[h] - mn);
          mrow[h] = mn;
          lrow[h] *= alpha;
          #pragma unroll
          for (int r = 0; r < 4; ++r) {
            int src = (lane & 48) | (quad * 4 + r);
            float ar = __shfl(alpha, src, 64);
            #pragma unroll
            for (int dt = 0; dt < 8; ++dt) o[h][dt][r] *= ar;
          }
        }

        float rs = 0.f;
        #pragma unroll
        for (int nt = 0; nt < 4; ++nt)
          #pragma unroll
          for (int r = 0; r < 4; ++r) {
            float p = exp2hw(acc[nt][h][r] - mrow[h]);
            acc[nt][h][r] = p; rs += p;
          }
        lrow[h] += rs;

        unsigned pk0_0 = cvtpk(acc[0][h][0], acc[0][h][1]), pk0_1 = cvtpk(acc[0][h][2], acc[0][h][3]);
        unsigned pk1_0 = cvtpk(acc[1][h][0], acc[1][h][1]), pk1_1 = cvtpk(acc[1][h][2], acc[1][h][3]);
        unsigned pk2_0 = cvtpk(acc[2][h][0], acc[2][h][1]), pk2_1 = cvtpk(acc[2][h][2], acc[2][h][3]);
        unsigned pk3_0 = cvtpk(acc[3][h][0], acc[3][h][1]), pk3_1 = cvtpk(acc[3][h][2], acc[3][h][3]);

        int4v p0, p1;
        #pragma unroll
        for (int jp = 0; jp < 4; ++jp) {
          int srcb = srcbase + 64 * (jp >> 1);
          int a0 = __builtin_amdgcn_ds_bpermute(srcb, (int)((jp & 1) ? pk0_1 : pk0_0));
          int a1 = __builtin_amdgcn_ds_bpermute(srcb, (int)((jp & 1) ? pk1_1 : pk1_0));
          int a2 = __builtin_amdgcn_ds_bpermute(srcb, (int)((jp & 1) ? pk2_1 : pk2_0));
          int a3 = __builtin_amdgcn_ds_bpermute(srcb, (int)((jp & 1) ? pk3_1 : pk3_0));
          p0[jp] = hi2 ? a1 : a0;
          p1[jp] = hi2 ? a3 : a2;
        }
        pf[h][0] = __builtin_bit_cast(bf16x8, p0);
        pf[h][1] = __builtin_bit_cast(bf16x8, p1);
      } else {
        int4v z = (int4v)(0);
        pf[0][0] = __builtin_bit_cast(bf16x8, z);
        pf[0][1] = __builtin_bit_cast(bf16x8, z);
      }
    }

    // ---- stage K(kt+1) into the free buffer NOW: frees ka/kc before PV.
    if (more) stage_k(&Klds[cur ^ 1][0]);
    if (more) load_v(kt + 1);            // issue V prefetch; latency under PV

    // ---- O += P V  (vf read once, used by both halves)
    __builtin_amdgcn_s_setprio(1);
    #pragma unroll
    for (int ks2 = 0; ks2 < 2; ++ks2) {
      #pragma unroll
      for (int dt = 0; dt < 8; ++dt) {
        int row = dt * 16 + l16;
        int f7 = (row ^ (row >> 3)) & 7;
        int bswz = (ks2 * 4 + quad) ^ f7;
        bf16x8 vf = *(const bf16x8*)(Vc + row * 128 + bswz * 16);
        o[0][dt] = __builtin_amdgcn_mfma_f32_16x16x32_bf16(pf[0][ks2], vf, o[0][dt], 0, 0, 0);
        o[1][dt] = __builtin_amdgcn_mfma_f32_16x16x32_bf16(pf[1][ks2], vf, o[1][dt], 0, 0, 0);
      }
    }
    __builtin_amdgcn_s_setprio(0);

    if (more) stage_v(&Vlds[cur ^ 1][0]);   // V(kt+1) staged; barrier at loop top
  }

  // ---- epilogue: reduce partial denominators, then O / l
  #pragma unroll
  for (int h = 0; h < 2; ++h) {
    float lr = lrow[h];
    lr += __shfl_xor(lr, 16, 64);
    lr += __shfl_xor(lr, 32, 64);
    float linv[4];
    #pragma unroll
    for (int r = 0; r < 4; ++r) {
      int src = (lane & 48) | (quad * 4 + r);
      linv[r] = 1.0f / __shfl(lr, src, 64);
    }
    float* ob = out + ((size_t)bh * Ss + qt * BM + h * 64 + wave * 16) * Dd;
    #pragma unroll
    for (int dt = 0; dt < 8; ++dt)
      #pragma unroll
      for (int r = 0; r < 4; ++r)
        ob[(quad * 4 + r) * Dd + dt * 16 + l16] = o[h][dt][r] * linv[r];
  }
}

extern "C" void kernel_launch(void* const* d_in, const int* in_sizes, int n_in,
                              void* d_out, int out_size, void* d_ws, size_t ws_size,
                              hipStream_t stream) {
  const float* q = (const float*)d_in[0];
  const float* k = (const float*)d_in[1];
  const float* v = (const float*)d_in[2];
  float* out = (float*)d_out;
  dim3 grid(Bb * Hh * NQT);   // 512
  dim3 block(256);
  hipLaunchKernelGGL(fa_fwd_kernel, grid, block, 0, stream, q, k, v, out);
}

// Round 4
// 185.892 us; speedup vs baseline: 1.3523x; 1.3523x over previous
//
#include <hip/hip_runtime.h>
#include <hip/hip_bf16.h>

// Causal flash attention fwd. B=2,H=16,S=2048,D=128, fp32 io, bf16 MFMA.
// R7: 32x32x16 MFMA restructure. One wave = 32 q-rows (BM=128, 4 waves),
// so each K/V ds_read_b128 feeds a 32k-FLOP MFMA (2x FLOP/LDS-byte vs R4)
// WITHOUT R5/R6's register blowup (half the MFMA count, no qf/pf duplication).
// 32x32 C-layout puts a full q-row in a lane pair: softmax = 1 shfl_xor(32),
// alpha/1/l are per-lane scalars (no broadcast shuffles). P transform =
// cvt_pk + v_permlane32_swap_b32 (VALU) -- the per-tile ds_bpermutes are gone
// from the LDS pipe. Double-buffered LDS, one barrier/iter, phase-split
// staging pinned by sched_barrier(0). Swizzles/staging identical to R4/R6.
constexpr int Bb = 2, Hh = 16, Ss = 2048, Dd = 128;
constexpr int BM = 128, BN = 64;
constexpr int NQT = Ss / BM;                       // 16
// 1/sqrt(128) * log2(e): scores in log2 units.
constexpr float SCALE = 0.088388347648318447f * 1.4426950408889634f;

typedef __attribute__((ext_vector_type(8))) short bf16x8;
typedef __attribute__((ext_vector_type(16))) float f32x16;
typedef __attribute__((ext_vector_type(4))) int int4v;

__device__ __forceinline__ unsigned cvtpk(float lo, float hi) {
  unsigned r;
  asm("v_cvt_pk_bf16_f32 %0, %1, %2" : "=v"(r) : "v"(lo), "v"(hi));
  return r;                                    // [15:0]=bf16(lo) [31:16]=bf16(hi), RNE
}
__device__ __forceinline__ float exp2hw(float x) {
  float r;
  asm("v_exp_f32 %0, %1" : "=v"(r) : "v"(x));  // hardware exp2
  return r;
}
// exchange x.lanes[32:63] <-> y.lanes[0:31]
__device__ __forceinline__ void permswap(unsigned &x, unsigned &y) {
  asm("v_permlane32_swap_b32 %0, %1" : "+v"(x), "+v"(y));
}
__device__ __forceinline__ float fcomp(float4 f, int j) {   // j is unroll-constant
  return j == 0 ? f.x : (j == 1 ? f.y : (j == 2 ? f.z : f.w));
}

__global__ __launch_bounds__(256, 2)
void fa_fwd_kernel(const float* __restrict__ q, const float* __restrict__ k,
                   const float* __restrict__ v, float* __restrict__ out) {
  // K tile row-major bf16: row=256B (16x16B blocks), block b at b^(row&15)
  __shared__ __align__(16) char Klds[2][BN * 256];    // 2 x 16 KB
  // V tile transposed Vt[d][key]: row=128B (8x16B blocks), block b at b^((d^(d>>3))&7)
  __shared__ __align__(16) char Vlds[2][Dd * 128];    // 2 x 16 KB

  const int tid = threadIdx.x;
  const int wave = tid >> 6, lane = tid & 63;
  const int l31 = lane & 31, hi = lane >> 5, hi4 = hi * 4;
  const int bid = blockIdx.x;
  const int bh = bid & 31;
  const int r2 = bid >> 5;
  // complementary pairing: qt(r2) + qt(r2^8) = 15 -> uniform per-CU work at
  // grid=512 (2 blocks/CU); heavy tiles launch first.
  const int qt = (r2 < 8) ? (15 - r2) : (r2 - 8);

  const float* qb = q + (size_t)bh * Ss * Dd;
  const float* kb = k + (size_t)bh * Ss * Dd;
  const float* vb = v + (size_t)bh * Ss * Dd;

  const int qv = wave * 32 + l31;        // local q-row this lane owns (col of S^T)

  // ---- Q fragments (scale*log2e folded).
  // B-operand of 32x32x16: lane holds col q = l31, k-elems d = 16ks + 8hi + j.
  bf16x8 qf[8];
  {
    const float* qr = qb + (size_t)(qt * BM + qv) * Dd + hi * 8;
    #pragma unroll
    for (int ks = 0; ks < 8; ++ks) {
      float4 a = *(const float4*)(qr + ks * 16);
      float4 b = *(const float4*)(qr + ks * 16 + 4);
      int4v t;
      t[0] = (int)cvtpk(a.x * SCALE, a.y * SCALE);
      t[1] = (int)cvtpk(a.z * SCALE, a.w * SCALE);
      t[2] = (int)cvtpk(b.x * SCALE, b.y * SCALE);
      t[3] = (int)cvtpk(b.z * SCALE, b.w * SCALE);
      qf[ks] = __builtin_bit_cast(bf16x8, t);
    }
  }

  // ---- staging geometry (constant per thread) — identical to R4/R6
  const int krow0 = tid >> 4;            // 0..15
  const int kblk  = tid & 15;            // block index = d/8
  const int kswz  = kblk ^ krow0;        // row&15 == krow0 for all i
  const int vkg = tid >> 5;              // 0..7  (keys vkg*8 .. +7)
  const int vdq = tid & 31;              // d0 = vdq*4

  float4 ka[4], kc[4];                   // K prefetch (QK^T phase only)
  float4 vr[8];                          // V prefetch (PV phase only)

  auto load_k = [&](int kt) {
    const float* Kg = kb + (size_t)(kt * BN) * Dd + kblk * 8;
    #pragma unroll
    for (int i = 0; i < 4; ++i) {
      ka[i] = *(const float4*)(Kg + (size_t)(krow0 + 16 * i) * Dd);
      kc[i] = *(const float4*)(Kg + (size_t)(krow0 + 16 * i) * Dd + 4);
    }
  };
  auto load_v = [&](int kt) {
    const float* Vg = vb + (size_t)(kt * BN + vkg * 8) * Dd + vdq * 4;
    #pragma unroll
    for (int r = 0; r < 8; ++r)
      vr[r] = *(const float4*)(Vg + (size_t)r * Dd);
  };

  auto stage_k = [&](char* Kb) {
    #pragma unroll
    for (int i = 0; i < 4; ++i) {
      int4v t;
      t[0] = (int)cvtpk(ka[i].x, ka[i].y);
      t[1] = (int)cvtpk(ka[i].z, ka[i].w);
      t[2] = (int)cvtpk(kc[i].x, kc[i].y);
      t[3] = (int)cvtpk(kc[i].z, kc[i].w);
      *(int4v*)(Kb + (krow0 + 16 * i) * 256 + kswz * 16) = t;
    }
  };
  auto stage_v = [&](char* Vb) {
    #pragma unroll
    for (int j = 0; j < 4; ++j) {
      int d = vdq * 4 + j;
      int f7 = (d ^ (d >> 3)) & 7;
      int4v t;
      t[0] = (int)cvtpk(fcomp(vr[0], j), fcomp(vr[1], j));
      t[1] = (int)cvtpk(fcomp(vr[2], j), fcomp(vr[3], j));
      t[2] = (int)cvtpk(fcomp(vr[4], j), fcomp(vr[5], j));
      t[3] = (int)cvtpk(fcomp(vr[6], j), fcomp(vr[7], j));
      *(int4v*)(Vb + d * 128 + (vkg ^ f7) * 16) = t;
    }
  };

  // O^T accumulators: o[dt] = O^T[d = dt*32 + rowpat][q = l31]
  f32x16 o[4];
  #pragma unroll
  for (int i = 0; i < 4; ++i) o[i] = (f32x16)(0.0f);
  float mrow = -3.0e38f, lrow = 0.0f;    // per-lane; lane pair (l,l+32) stays consistent

  load_k(0); load_v(0);
  stage_k(&Klds[0][0]); stage_v(&Vlds[0][0]);

  const int nkt = 2 * qt + 2;

  for (int kt = 0; kt < nkt; ++kt) {
    __syncthreads();                     // buf[cur] staged; buf[cur^1] free
    const int cur = kt & 1;
    const char* Kc = &Klds[cur][0];
    const char* Vc = &Vlds[cur][0];
    const bool more = kt + 1 < nkt;
    if (more) load_k(kt + 1);            // issue K prefetch (latency under QK^T)

    const int thr = qt * 128 + qv - kt * 64;               // causal threshold (per lane)
    const bool live = (qt * 128 + wave * 32 + 31 - kt * 64) >= 0;  // wave-uniform

    bf16x8 pf[4];                        // P^T B-frags, key-slice ks2
    if (live) {
      // ---- S^T = K Q^T. A = K[key=t*32+l31][d=16ks+8hi+j]; D col=q=l31,
      // row(key) = t*32 + (reg&3) + 8*(reg>>2) + 4*hi.
      f32x16 acc[2];
      acc[0] = (f32x16)(0.0f); acc[1] = (f32x16)(0.0f);
      __builtin_amdgcn_s_setprio(1);
      #pragma unroll
      for (int ks = 0; ks < 8; ++ks) {
        #pragma unroll
        for (int t = 0; t < 2; ++t) {
          int row = t * 32 + l31;
          int bswz = (2 * ks + hi) ^ (row & 15);
          bf16x8 kf = *(const bf16x8*)(Kc + row * 256 + bswz * 16);
          acc[t] = __builtin_amdgcn_mfma_f32_32x32x16_bf16(kf, qf[ks], acc[t], 0, 0, 0);
        }
      }
      __builtin_amdgcn_s_setprio(0);

      // ---- causal mask (diagonal tiles only). thr uniform over a lane's regs.
      if (kt + 2 >= nkt) {
        #pragma unroll
        for (int t = 0; t < 2; ++t)
          #pragma unroll
          for (int r = 0; r < 16; ++r) {
            int key = t * 32 + (r & 3) + 8 * (r >> 2) + hi4;
            if (key > thr) acc[t][r] = -1.0e30f;
          }
      }

      // ---- online softmax (log2 domain). Lane pair (l, l+32) shares q=l31:
      // one shfl_xor(32) gives the true row max; alpha/l are per-lane scalars.
      float mx = acc[0][0];
      #pragma unroll
      for (int t = 0; t < 2; ++t)
        #pragma unroll
        for (int r = 0; r < 16; ++r) mx = fmaxf(mx, acc[t][r]);
      mx = fmaxf(mx, __shfl_xor(mx, 32, 64));

      if (!__all(mx - mrow <= 8.0f)) {   // defer-max, THR=8 (log2)
        float mn = fmaxf(mrow, mx);
        float al = exp2hw(mrow - mn);
        mrow = mn;
        lrow *= al;
        #pragma unroll
        for (int dt = 0; dt < 4; ++dt)
          #pragma unroll
          for (int r = 0; r < 16; ++r) o[dt][r] *= al;
      }

      float rs = 0.f;
      #pragma unroll
      for (int t = 0; t < 2; ++t)
        #pragma unroll
        for (int r = 0; r < 16; ++r) {
          float p = exp2hw(acc[t][r] - mrow);
          acc[t][r] = p; rs += p;
        }
      lrow += rs;                        // per-lane partial (this lane's 32 keys)

      // ---- P^T B-frags: dest lane (q=l31, g=hi) needs keys 16*ks2+8g+j.
      // j0..3 live in lo partner, j4..7 in hi partner, regs {0..3}+4*(2s+g).
      // permswap(A0,B0) -> (w0,w2); permswap(A1,B1) -> (w1,w3).
      #pragma unroll
      for (int ks2 = 0; ks2 < 4; ++ks2) {
        int t = ks2 >> 1, s8 = (ks2 & 1) * 8;
        unsigned A0 = cvtpk(acc[t][s8 + 0], acc[t][s8 + 1]);
        unsigned A1 = cvtpk(acc[t][s8 + 2], acc[t][s8 + 3]);
        unsigned B0 = cvtpk(acc[t][s8 + 4], acc[t][s8 + 5]);
        unsigned B1 = cvtpk(acc[t][s8 + 6], acc[t][s8 + 7]);
        permswap(A0, B0);
        permswap(A1, B1);
        int4v pw; pw[0] = (int)A0; pw[1] = (int)A1; pw[2] = (int)B0; pw[3] = (int)B1;
        pf[ks2] = __builtin_bit_cast(bf16x8, pw);
      }
    }

    // ---- stage K(kt+1) NOW (frees ka/kc); fence stops load_v hoisting above.
    if (more) stage_k(&Klds[cur ^ 1][0]);
    __builtin_amdgcn_sched_barrier(0);
    if (more) load_v(kt + 1);            // issue V prefetch; latency under PV

    // ---- O^T += V^T P^T. A = Vt[d=dt*32+l31][key=16ks2+8hi+j].
    if (live) {
      __builtin_amdgcn_s_setprio(1);
      #pragma unroll
      for (int dt = 0; dt < 4; ++dt) {
        int row = dt * 32 + l31;
        int f7 = (row ^ (row >> 3)) & 7;
        #pragma unroll
        for (int ks2 = 0; ks2 < 4; ++ks2) {
          int bswz = (2 * ks2 + hi) ^ f7;
          bf16x8 vf = *(const bf16x8*)(Vc + row * 128 + bswz * 16);
          o[dt] = __builtin_amdgcn_mfma_f32_32x32x16_bf16(vf, pf[ks2], o[dt], 0, 0, 0);
        }
      }
      __builtin_amdgcn_s_setprio(0);
    }

    if (more) stage_v(&Vlds[cur ^ 1][0]);   // V(kt+1) staged; barrier at loop top
  }

  // ---- epilogue: pair-reduce denominator; per-lane scalar 1/l; store O^T.
  lrow += __shfl_xor(lrow, 32, 64);
  const float linv = 1.0f / lrow;
  float* ob = out + ((size_t)bh * Ss + qt * BM + qv) * Dd;
  #pragma unroll
  for (int dt = 0; dt < 4; ++dt)
    #pragma unroll
    for (int g = 0; g < 4; ++g) {
      float4 w;
      w.x = o[dt][g * 4 + 0] * linv;
      w.y = o[dt][g * 4 + 1] * linv;
      w.z = o[dt][g * 4 + 2] * linv;
      w.w = o[dt][g * 4 + 3] * linv;
      *(float4*)(ob + dt * 32 + g * 8 + hi4) = w;   // d = dt*32 + 8g + 4hi + c
    }
}

extern "C" void kernel_launch(void* const* d_in, const int* in_sizes, int n_in,
                              void* d_out, int out_size, void* d_ws, size_t ws_size,
                              hipStream_t stream) {
  const float* q = (const float*)d_in[0];
  const float* k = (const float*)d_in[1];
  const float* v = (const float*)d_in[2];
  float* out = (float*)d_out;
  dim3 grid(Bb * Hh * NQT);   // 512
  dim3 block(256);
  hipLaunchKernelGGL(fa_fwd_kernel, grid, block, 0, stream, q, k, v, out);
}

// Round 5
// 184.729 us; speedup vs baseline: 1.3608x; 1.0063x over previous
//
#include <hip/hip_runtime.h>
#include <hip/hip_bf16.h>

// Causal flash attention fwd. B=2,H=16,S=2048,D=128, fp32 io, bf16 MFMA.
// R8: R7 (32x32x16, zero bank conflicts, no spill) + full-iteration prefetch
// distance. R7 stalled ~850 cyc/iter in vmcnt waits: load_k issued at loop
// top was consumed ~550 cyc later (HBM ~900 cyc), load_v issued mid-iter
// consumed ~400 cyc later. Now each load_X(kt+2) is issued immediately after
// stage_X(kt+1) frees its registers -> ~1 full iteration of slack before the
// consuming wait. sched_barrier(0) pins the cluster so the compiler can't
// rename-hoist loads upward (R6's spill mechanism). Everything else from R7.
constexpr int Bb = 2, Hh = 16, Ss = 2048, Dd = 128;
constexpr int BM = 128, BN = 64;
constexpr int NQT = Ss / BM;                       // 16
// 1/sqrt(128) * log2(e): scores in log2 units.
constexpr float SCALE = 0.088388347648318447f * 1.4426950408889634f;

typedef __attribute__((ext_vector_type(8))) short bf16x8;
typedef __attribute__((ext_vector_type(16))) float f32x16;
typedef __attribute__((ext_vector_type(4))) int int4v;

__device__ __forceinline__ unsigned cvtpk(float lo, float hi) {
  unsigned r;
  asm("v_cvt_pk_bf16_f32 %0, %1, %2" : "=v"(r) : "v"(lo), "v"(hi));
  return r;                                    // [15:0]=bf16(lo) [31:16]=bf16(hi), RNE
}
__device__ __forceinline__ float exp2hw(float x) {
  float r;
  asm("v_exp_f32 %0, %1" : "=v"(r) : "v"(x));  // hardware exp2
  return r;
}
// exchange x.lanes[32:63] <-> y.lanes[0:31]
__device__ __forceinline__ void permswap(unsigned &x, unsigned &y) {
  asm("v_permlane32_swap_b32 %0, %1" : "+v"(x), "+v"(y));
}
__device__ __forceinline__ float fcomp(float4 f, int j) {   // j is unroll-constant
  return j == 0 ? f.x : (j == 1 ? f.y : (j == 2 ? f.z : f.w));
}

__global__ __launch_bounds__(256, 2)
void fa_fwd_kernel(const float* __restrict__ q, const float* __restrict__ k,
                   const float* __restrict__ v, float* __restrict__ out) {
  // K tile row-major bf16: row=256B (16x16B blocks), block b at b^(row&15)
  __shared__ __align__(16) char Klds[2][BN * 256];    // 2 x 16 KB
  // V tile transposed Vt[d][key]: row=128B (8x16B blocks), block b at b^((d^(d>>3))&7)
  __shared__ __align__(16) char Vlds[2][Dd * 128];    // 2 x 16 KB

  const int tid = threadIdx.x;
  const int wave = tid >> 6, lane = tid & 63;
  const int l31 = lane & 31, hi = lane >> 5, hi4 = hi * 4;
  const int bid = blockIdx.x;
  const int bh = bid & 31;
  const int r2 = bid >> 5;
  // complementary pairing: qt(r2) + qt(r2^8) = 15 -> uniform per-CU work at
  // grid=512 (2 blocks/CU); heavy tiles launch first.
  const int qt = (r2 < 8) ? (15 - r2) : (r2 - 8);

  const float* qb = q + (size_t)bh * Ss * Dd;
  const float* kb = k + (size_t)bh * Ss * Dd;
  const float* vb = v + (size_t)bh * Ss * Dd;

  const int qv = wave * 32 + l31;        // local q-row this lane owns (col of S^T)

  // ---- Q fragments (scale*log2e folded).
  // B-operand of 32x32x16: lane holds col q = l31, k-elems d = 16ks + 8hi + j.
  bf16x8 qf[8];
  {
    const float* qr = qb + (size_t)(qt * BM + qv) * Dd + hi * 8;
    #pragma unroll
    for (int ks = 0; ks < 8; ++ks) {
      float4 a = *(const float4*)(qr + ks * 16);
      float4 b = *(const float4*)(qr + ks * 16 + 4);
      int4v t;
      t[0] = (int)cvtpk(a.x * SCALE, a.y * SCALE);
      t[1] = (int)cvtpk(a.z * SCALE, a.w * SCALE);
      t[2] = (int)cvtpk(b.x * SCALE, b.y * SCALE);
      t[3] = (int)cvtpk(b.z * SCALE, b.w * SCALE);
      qf[ks] = __builtin_bit_cast(bf16x8, t);
    }
  }

  // ---- staging geometry (constant per thread) — identical to R7
  const int krow0 = tid >> 4;            // 0..15
  const int kblk  = tid & 15;            // block index = d/8
  const int kswz  = kblk ^ krow0;        // row&15 == krow0 for all i
  const int vkg = tid >> 5;              // 0..7  (keys vkg*8 .. +7)
  const int vdq = tid & 31;              // d0 = vdq*4

  float4 ka[4], kc[4];                   // K prefetch regs (one set, always in flight)
  float4 vr[8];                          // V prefetch regs (one set, always in flight)

  auto load_k = [&](int kt) {
    const float* Kg = kb + (size_t)(kt * BN) * Dd + kblk * 8;
    #pragma unroll
    for (int i = 0; i < 4; ++i) {
      ka[i] = *(const float4*)(Kg + (size_t)(krow0 + 16 * i) * Dd);
      kc[i] = *(const float4*)(Kg + (size_t)(krow0 + 16 * i) * Dd + 4);
    }
  };
  auto load_v = [&](int kt) {
    const float* Vg = vb + (size_t)(kt * BN + vkg * 8) * Dd + vdq * 4;
    #pragma unroll
    for (int r = 0; r < 8; ++r)
      vr[r] = *(const float4*)(Vg + (size_t)r * Dd);
  };

  auto stage_k = [&](char* Kb) {
    #pragma unroll
    for (int i = 0; i < 4; ++i) {
      int4v t;
      t[0] = (int)cvtpk(ka[i].x, ka[i].y);
      t[1] = (int)cvtpk(ka[i].z, ka[i].w);
      t[2] = (int)cvtpk(kc[i].x, kc[i].y);
      t[3] = (int)cvtpk(kc[i].z, kc[i].w);
      *(int4v*)(Kb + (krow0 + 16 * i) * 256 + kswz * 16) = t;
    }
  };
  auto stage_v = [&](char* Vb) {
    #pragma unroll
    for (int j = 0; j < 4; ++j) {
      int d = vdq * 4 + j;
      int f7 = (d ^ (d >> 3)) & 7;
      int4v t;
      t[0] = (int)cvtpk(fcomp(vr[0], j), fcomp(vr[1], j));
      t[1] = (int)cvtpk(fcomp(vr[2], j), fcomp(vr[3], j));
      t[2] = (int)cvtpk(fcomp(vr[4], j), fcomp(vr[5], j));
      t[3] = (int)cvtpk(fcomp(vr[6], j), fcomp(vr[7], j));
      *(int4v*)(Vb + d * 128 + (vkg ^ f7) * 16) = t;
    }
  };

  // O^T accumulators: o[dt] = O^T[d = dt*32 + rowpat][q = l31]
  f32x16 o[4];
  #pragma unroll
  for (int i = 0; i < 4; ++i) o[i] = (f32x16)(0.0f);
  float mrow = -3.0e38f, lrow = 0.0f;    // per-lane; lane pair (l,l+32) stays consistent

  const int nkt = 2 * qt + 2;

  // ---- prologue: tile 0 staged; tile 1 loads already in flight.
  load_k(0); load_v(0);
  stage_k(&Klds[0][0]); stage_v(&Vlds[0][0]);
  load_k(1); load_v(1);                  // nkt >= 2 always

  for (int kt = 0; kt < nkt; ++kt) {
    __syncthreads();                     // buf[cur] staged; buf[cur^1] free
    const int cur = kt & 1;
    const char* Kc = &Klds[cur][0];
    const char* Vc = &Vlds[cur][0];
    const bool more = kt + 1 < nkt;
    const int kn = (kt + 2 < nkt) ? kt + 2 : nkt - 1;   // clamped next-next tile

    const int thr = qt * 128 + qv - kt * 64;               // causal threshold (per lane)
    const bool live = (qt * 128 + wave * 32 + 31 - kt * 64) >= 0;  // wave-uniform

    bf16x8 pf[4];                        // P^T B-frags, key-slice ks2
    if (live) {
      // ---- S^T = K Q^T. A = K[key=t*32+l31][d=16ks+8hi+j]; D col=q=l31,
      // row(key) = t*32 + (reg&3) + 8*(reg>>2) + 4*hi.
      f32x16 acc[2];
      acc[0] = (f32x16)(0.0f); acc[1] = (f32x16)(0.0f);
      __builtin_amdgcn_s_setprio(1);
      #pragma unroll
      for (int ks = 0; ks < 8; ++ks) {
        #pragma unroll
        for (int t = 0; t < 2; ++t) {
          int row = t * 32 + l31;
          int bswz = (2 * ks + hi) ^ (row & 15);
          bf16x8 kf = *(const bf16x8*)(Kc + row * 256 + bswz * 16);
          acc[t] = __builtin_amdgcn_mfma_f32_32x32x16_bf16(kf, qf[ks], acc[t], 0, 0, 0);
        }
      }
      __builtin_amdgcn_s_setprio(0);

      // ---- causal mask (diagonal tiles only). thr uniform over a lane's regs.
      if (kt + 2 >= nkt) {
        #pragma unroll
        for (int t = 0; t < 2; ++t)
          #pragma unroll
          for (int r = 0; r < 16; ++r) {
            int key = t * 32 + (r & 3) + 8 * (r >> 2) + hi4;
            if (key > thr) acc[t][r] = -1.0e30f;
          }
      }

      // ---- online softmax (log2 domain). Lane pair (l, l+32) shares q=l31:
      // one shfl_xor(32) gives the true row max; alpha/l are per-lane scalars.
      float mx = acc[0][0];
      #pragma unroll
      for (int t = 0; t < 2; ++t)
        #pragma unroll
        for (int r = 0; r < 16; ++r) mx = fmaxf(mx, acc[t][r]);
      mx = fmaxf(mx, __shfl_xor(mx, 32, 64));

      if (!__all(mx - mrow <= 8.0f)) {   // defer-max, THR=8 (log2)
        float mn = fmaxf(mrow, mx);
        float al = exp2hw(mrow - mn);
        mrow = mn;
        lrow *= al;
        #pragma unroll
        for (int dt = 0; dt < 4; ++dt)
          #pragma unroll
          for (int r = 0; r < 16; ++r) o[dt][r] *= al;
      }

      float rs = 0.f;
      #pragma unroll
      for (int t = 0; t < 2; ++t)
        #pragma unroll
        for (int r = 0; r < 16; ++r) {
          float p = exp2hw(acc[t][r] - mrow);
          acc[t][r] = p; rs += p;
        }
      lrow += rs;                        // per-lane partial (this lane's 32 keys)

      // ---- P^T B-frags: dest lane (q=l31, g=hi) needs keys 16*ks2+8g+j.
      // j0..3 live in lo partner, j4..7 in hi partner, regs {0..3}+4*(2s+g).
      // permswap(A0,B0) -> (w0,w2); permswap(A1,B1) -> (w1,w3).
      #pragma unroll
      for (int ks2 = 0; ks2 < 4; ++ks2) {
        int t = ks2 >> 1, s8 = (ks2 & 1) * 8;
        unsigned A0 = cvtpk(acc[t][s8 + 0], acc[t][s8 + 1]);
        unsigned A1 = cvtpk(acc[t][s8 + 2], acc[t][s8 + 3]);
        unsigned B0 = cvtpk(acc[t][s8 + 4], acc[t][s8 + 5]);
        unsigned B1 = cvtpk(acc[t][s8 + 6], acc[t][s8 + 7]);
        permswap(A0, B0);
        permswap(A1, B1);
        int4v pw; pw[0] = (int)A0; pw[1] = (int)A1; pw[2] = (int)B0; pw[3] = (int)B1;
        pf[ks2] = __builtin_bit_cast(bf16x8, pw);
      }
    }

    // ---- stage K(kt+1) (consumes ka/kc, waits its loads from one iter ago),
    // then IMMEDIATELY issue load_k(kt+2) into the freed regs. sched_barrier
    // pins the cluster so the loads can't be rename-hoisted upward (R6 bug).
    if (more) {
      __builtin_amdgcn_sched_barrier(0);
      stage_k(&Klds[cur ^ 1][0]);
      load_k(kn);
      __builtin_amdgcn_sched_barrier(0);
    }

    // ---- O^T += V^T P^T. A = Vt[d=dt*32+l31][key=16ks2+8hi+j].
    if (live) {
      __builtin_amdgcn_s_setprio(1);
      #pragma unroll
      for (int dt = 0; dt < 4; ++dt) {
        int row = dt * 32 + l31;
        int f7 = (row ^ (row >> 3)) & 7;
        #pragma unroll
        for (int ks2 = 0; ks2 < 4; ++ks2) {
          int bswz = (2 * ks2 + hi) ^ f7;
          bf16x8 vf = *(const bf16x8*)(Vc + row * 128 + bswz * 16);
          o[dt] = __builtin_amdgcn_mfma_f32_32x32x16_bf16(vf, pf[ks2], o[dt], 0, 0, 0);
        }
      }
      __builtin_amdgcn_s_setprio(0);
    }

    // ---- stage V(kt+1) (waits V loads from one iter ago), then issue
    // load_v(kt+2). Barrier at loop top publishes buf^1.
    if (more) {
      __builtin_amdgcn_sched_barrier(0);
      stage_v(&Vlds[cur ^ 1][0]);
      load_v(kn);
    }
  }

  // ---- epilogue: pair-reduce denominator; per-lane scalar 1/l; store O^T.
  lrow += __shfl_xor(lrow, 32, 64);
  const float linv = 1.0f / lrow;
  float* ob = out + ((size_t)bh * Ss + qt * BM + qv) * Dd;
  #pragma unroll
  for (int dt = 0; dt < 4; ++dt)
    #pragma unroll
    for (int g = 0; g < 4; ++g) {
      float4 w;
      w.x = o[dt][g * 4 + 0] * linv;
      w.y = o[dt][g * 4 + 1] * linv;
      w.z = o[dt][g * 4 + 2] * linv;
      w.w = o[dt][g * 4 + 3] * linv;
      *(float4*)(ob + dt * 32 + g * 8 + hi4) = w;   // d = dt*32 + 8g + 4hi + c
    }
}

extern "C" void kernel_launch(void* const* d_in, const int* in_sizes, int n_in,
                              void* d_out, int out_size, void* d_ws, size_t ws_size,
                              hipStream_t stream) {
  const float* q = (const float*)d_in[0];
  const float* k = (const float*)d_in[1];
  const float* v = (const float*)d_in[2];
  float* out = (float*)d_out;
  dim3 grid(Bb * Hh * NQT);   // 512
  dim3 block(256);
  hipLaunchKernelGGL(fa_fwd_kernel, grid, block, 0, stream, q, k, v, out);
}

// Round 7
// 183.858 us; speedup vs baseline: 1.3673x; 1.0047x over previous
//
#include <hip/hip_runtime.h>
#include <hip/hip_bf16.h>

// Causal flash attention fwd. B=2,H=16,S=2048,D=128, fp32 io, bf16 MFMA.
// R9 (resubmit; previous round was a container-acquisition failure, no data).
// __syncthreads() emits s_waitcnt vmcnt(0) lgkmcnt(0) before s_barrier ->
// every iteration drained the in-flight prefetch loads (R8's full-iteration
// prefetch distance was nullified; R8 == R7 in every counter). Replaced with
// raw s_barrier + lgkmcnt(0) only (LDS-write visibility): global prefetch
// loads stay in flight across the barrier, consumed by stage_* a full
// iteration later with compiler-inserted counted vmcnt. Also: 4-way tree
// partials for softmax max/sum (was 31/32-long dependent chains, exposed at
// low occupancy). Everything else (32x32x16, swizzles, permlane P-transform,
// defer-max, dbuf LDS, phase-split staging) identical to R8.
constexpr int Bb = 2, Hh = 16, Ss = 2048, Dd = 128;
constexpr int BM = 128, BN = 64;
constexpr int NQT = Ss / BM;                       // 16
// 1/sqrt(128) * log2(e): scores in log2 units.
constexpr float SCALE = 0.088388347648318447f * 1.4426950408889634f;

typedef __attribute__((ext_vector_type(8))) short bf16x8;
typedef __attribute__((ext_vector_type(16))) float f32x16;
typedef __attribute__((ext_vector_type(4))) int int4v;

__device__ __forceinline__ unsigned cvtpk(float lo, float hi) {
  unsigned r;
  asm("v_cvt_pk_bf16_f32 %0, %1, %2" : "=v"(r) : "v"(lo), "v"(hi));
  return r;                                    // [15:0]=bf16(lo) [31:16]=bf16(hi), RNE
}
__device__ __forceinline__ float exp2hw(float x) {
  float r;
  asm("v_exp_f32 %0, %1" : "=v"(r) : "v"(x));  // hardware exp2
  return r;
}
// exchange x.lanes[32:63] <-> y.lanes[0:31]
__device__ __forceinline__ void permswap(unsigned &x, unsigned &y) {
  asm("v_permlane32_swap_b32 %0, %1" : "+v"(x), "+v"(y));
}
__device__ __forceinline__ float fcomp(float4 f, int j) {   // j is unroll-constant
  return j == 0 ? f.x : (j == 1 ? f.y : (j == 2 ? f.z : f.w));
}
// Barrier WITHOUT vmcnt drain: only LDS writes must be visible. In-flight
// global prefetch loads (wave-private register dests) cross the barrier.
__device__ __forceinline__ void block_sync_lds() {
  __builtin_amdgcn_sched_barrier(0);
  asm volatile("s_waitcnt lgkmcnt(0)" ::: "memory");
  __builtin_amdgcn_s_barrier();
  __builtin_amdgcn_sched_barrier(0);
}

__global__ __launch_bounds__(256, 2)
void fa_fwd_kernel(const float* __restrict__ q, const float* __restrict__ k,
                   const float* __restrict__ v, float* __restrict__ out) {
  // K tile row-major bf16: row=256B (16x16B blocks), block b at b^(row&15)
  __shared__ __align__(16) char Klds[2][BN * 256];    // 2 x 16 KB
  // V tile transposed Vt[d][key]: row=128B (8x16B blocks), block b at b^((d^(d>>3))&7)
  __shared__ __align__(16) char Vlds[2][Dd * 128];    // 2 x 16 KB

  const int tid = threadIdx.x;
  const int wave = tid >> 6, lane = tid & 63;
  const int l31 = lane & 31, hi = lane >> 5, hi4 = hi * 4;
  const int bid = blockIdx.x;
  const int bh = bid & 31;
  const int r2 = bid >> 5;
  // complementary pairing: qt(r2) + qt(r2^8) = 15 -> uniform per-CU work at
  // grid=512 (2 blocks/CU); heavy tiles launch first.
  const int qt = (r2 < 8) ? (15 - r2) : (r2 - 8);

  const float* qb = q + (size_t)bh * Ss * Dd;
  const float* kb = k + (size_t)bh * Ss * Dd;
  const float* vb = v + (size_t)bh * Ss * Dd;

  const int qv = wave * 32 + l31;        // local q-row this lane owns (col of S^T)

  // ---- Q fragments (scale*log2e folded).
  // B-operand of 32x32x16: lane holds col q = l31, k-elems d = 16ks + 8hi + j.
  bf16x8 qf[8];
  {
    const float* qr = qb + (size_t)(qt * BM + qv) * Dd + hi * 8;
    #pragma unroll
    for (int ks = 0; ks < 8; ++ks) {
      float4 a = *(const float4*)(qr + ks * 16);
      float4 b = *(const float4*)(qr + ks * 16 + 4);
      int4v t;
      t[0] = (int)cvtpk(a.x * SCALE, a.y * SCALE);
      t[1] = (int)cvtpk(a.z * SCALE, a.w * SCALE);
      t[2] = (int)cvtpk(b.x * SCALE, b.y * SCALE);
      t[3] = (int)cvtpk(b.z * SCALE, b.w * SCALE);
      qf[ks] = __builtin_bit_cast(bf16x8, t);
    }
  }

  // ---- staging geometry (constant per thread) — identical to R7/R8
  const int krow0 = tid >> 4;            // 0..15
  const int kblk  = tid & 15;            // block index = d/8
  const int kswz  = kblk ^ krow0;        // row&15 == krow0 for all i
  const int vkg = tid >> 5;              // 0..7  (keys vkg*8 .. +7)
  const int vdq = tid & 31;              // d0 = vdq*4

  float4 ka[4], kc[4];                   // K prefetch regs (one set, always in flight)
  float4 vr[8];                          // V prefetch regs (one set, always in flight)

  auto load_k = [&](int kt) {
    const float* Kg = kb + (size_t)(kt * BN) * Dd + kblk * 8;
    #pragma unroll
    for (int i = 0; i < 4; ++i) {
      ka[i] = *(const float4*)(Kg + (size_t)(krow0 + 16 * i) * Dd);
      kc[i] = *(const float4*)(Kg + (size_t)(krow0 + 16 * i) * Dd + 4);
    }
  };
  auto load_v = [&](int kt) {
    const float* Vg = vb + (size_t)(kt * BN + vkg * 8) * Dd + vdq * 4;
    #pragma unroll
    for (int r = 0; r < 8; ++r)
      vr[r] = *(const float4*)(Vg + (size_t)r * Dd);
  };

  auto stage_k = [&](char* Kb) {
    #pragma unroll
    for (int i = 0; i < 4; ++i) {
      int4v t;
      t[0] = (int)cvtpk(ka[i].x, ka[i].y);
      t[1] = (int)cvtpk(ka[i].z, ka[i].w);
      t[2] = (int)cvtpk(kc[i].x, kc[i].y);
      t[3] = (int)cvtpk(kc[i].z, kc[i].w);
      *(int4v*)(Kb + (krow0 + 16 * i) * 256 + kswz * 16) = t;
    }
  };
  auto stage_v = [&](char* Vb) {
    #pragma unroll
    for (int j = 0; j < 4; ++j) {
      int d = vdq * 4 + j;
      int f7 = (d ^ (d >> 3)) & 7;
      int4v t;
      t[0] = (int)cvtpk(fcomp(vr[0], j), fcomp(vr[1], j));
      t[1] = (int)cvtpk(fcomp(vr[2], j), fcomp(vr[3], j));
      t[2] = (int)cvtpk(fcomp(vr[4], j), fcomp(vr[5], j));
      t[3] = (int)cvtpk(fcomp(vr[6], j), fcomp(vr[7], j));
      *(int4v*)(Vb + d * 128 + (vkg ^ f7) * 16) = t;
    }
  };

  // O^T accumulators: o[dt] = O^T[d = dt*32 + rowpat][q = l31]
  f32x16 o[4];
  #pragma unroll
  for (int i = 0; i < 4; ++i) o[i] = (f32x16)(0.0f);
  float mrow = -3.0e38f, lrow = 0.0f;    // per-lane; lane pair (l,l+32) stays consistent

  const int nkt = 2 * qt + 2;

  // ---- prologue: tile 0 staged; tile 1 loads already in flight.
  load_k(0); load_v(0);
  stage_k(&Klds[0][0]); stage_v(&Vlds[0][0]);
  load_k(1); load_v(1);                  // nkt >= 2 always

  for (int kt = 0; kt < nkt; ++kt) {
    block_sync_lds();                    // buf[cur] staged; prefetch loads stay in flight
    const int cur = kt & 1;
    const char* Kc = &Klds[cur][0];
    const char* Vc = &Vlds[cur][0];
    const bool more = kt + 1 < nkt;
    const int kn = (kt + 2 < nkt) ? kt + 2 : nkt - 1;   // clamped next-next tile

    const int thr = qt * 128 + qv - kt * 64;               // causal threshold (per lane)
    const bool live = (qt * 128 + wave * 32 + 31 - kt * 64) >= 0;  // wave-uniform

    bf16x8 pf[4];                        // P^T B-frags, key-slice ks2
    if (live) {
      // ---- S^T = K Q^T. A = K[key=t*32+l31][d=16ks+8hi+j]; D col=q=l31,
      // row(key) = t*32 + (reg&3) + 8*(reg>>2) + 4*hi.
      f32x16 acc[2];
      acc[0] = (f32x16)(0.0f); acc[1] = (f32x16)(0.0f);
      __builtin_amdgcn_s_setprio(1);
      #pragma unroll
      for (int ks = 0; ks < 8; ++ks) {
        #pragma unroll
        for (int t = 0; t < 2; ++t) {
          int row = t * 32 + l31;
          int bswz = (2 * ks + hi) ^ (row & 15);
          bf16x8 kf = *(const bf16x8*)(Kc + row * 256 + bswz * 16);
          acc[t] = __builtin_amdgcn_mfma_f32_32x32x16_bf16(kf, qf[ks], acc[t], 0, 0, 0);
        }
      }
      __builtin_amdgcn_s_setprio(0);

      // ---- causal mask (diagonal tiles only). thr uniform over a lane's regs.
      if (kt + 2 >= nkt) {
        #pragma unroll
        for (int t = 0; t < 2; ++t)
          #pragma unroll
          for (int r = 0; r < 16; ++r) {
            int key = t * 32 + (r & 3) + 8 * (r >> 2) + hi4;
            if (key > thr) acc[t][r] = -1.0e30f;
          }
      }

      // ---- online softmax (log2 domain). Lane pair (l, l+32) shares q=l31.
      // 4-way tree partials: dependency depth ~8+2 instead of 31.
      float mp0 = acc[0][0], mp1 = acc[0][1], mp2 = acc[0][2], mp3 = acc[0][3];
      #pragma unroll
      for (int t = 0; t < 2; ++t)
        #pragma unroll
        for (int r = (t == 0 ? 4 : 0); r < 16; r += 4) {
          mp0 = fmaxf(mp0, acc[t][r + 0]);
          mp1 = fmaxf(mp1, acc[t][r + 1]);
          mp2 = fmaxf(mp2, acc[t][r + 2]);
          mp3 = fmaxf(mp3, acc[t][r + 3]);
        }
      float mx = fmaxf(fmaxf(mp0, mp1), fmaxf(mp2, mp3));
      mx = fmaxf(mx, __shfl_xor(mx, 32, 64));

      if (!__all(mx - mrow <= 8.0f)) {   // defer-max, THR=8 (log2)
        float mn = fmaxf(mrow, mx);
        float al = exp2hw(mrow - mn);
        mrow = mn;
        lrow *= al;
        #pragma unroll
        for (int dt = 0; dt < 4; ++dt)
          #pragma unroll
          for (int r = 0; r < 16; ++r) o[dt][r] *= al;
      }

      float rp0 = 0.f, rp1 = 0.f, rp2 = 0.f, rp3 = 0.f;
      #pragma unroll
      for (int t = 0; t < 2; ++t)
        #pragma unroll
        for (int r = 0; r < 16; r += 4) {
          float p0 = exp2hw(acc[t][r + 0] - mrow);
          float p1 = exp2hw(acc[t][r + 1] - mrow);
          float p2 = exp2hw(acc[t][r + 2] - mrow);
          float p3 = exp2hw(acc[t][r + 3] - mrow);
          acc[t][r + 0] = p0; acc[t][r + 1] = p1;
          acc[t][r + 2] = p2; acc[t][r + 3] = p3;
          rp0 += p0; rp1 += p1; rp2 += p2; rp3 += p3;
        }
      lrow += (rp0 + rp1) + (rp2 + rp3);  // per-lane partial (this lane's 32 keys)

      // ---- P^T B-frags: dest lane (q=l31, g=hi) needs keys 16*ks2+8g+j.
      // j0..3 live in lo partner, j4..7 in hi partner, regs {0..3}+4*(2s+g).
      // permswap(A0,B0) -> (w0,w2); permswap(A1,B1) -> (w1,w3).
      #pragma unroll
      for (int ks2 = 0; ks2 < 4; ++ks2) {
        int t = ks2 >> 1, s8 = (ks2 & 1) * 8;
        unsigned A0 = cvtpk(acc[t][s8 + 0], acc[t][s8 + 1]);
        unsigned A1 = cvtpk(acc[t][s8 + 2], acc[t][s8 + 3]);
        unsigned B0 = cvtpk(acc[t][s8 + 4], acc[t][s8 + 5]);
        unsigned B1 = cvtpk(acc[t][s8 + 6], acc[t][s8 + 7]);
        permswap(A0, B0);
        permswap(A1, B1);
        int4v pw; pw[0] = (int)A0; pw[1] = (int)A1; pw[2] = (int)B0; pw[3] = (int)B1;
        pf[ks2] = __builtin_bit_cast(bf16x8, pw);
      }
    }

    // ---- stage K(kt+1) (waits its loads from one iter ago via counted vmcnt),
    // then IMMEDIATELY issue load_k(kt+2) into the freed regs.
    if (more) {
      __builtin_amdgcn_sched_barrier(0);
      stage_k(&Klds[cur ^ 1][0]);
      load_k(kn);
      __builtin_amdgcn_sched_barrier(0);
    }

    // ---- O^T += V^T P^T. A = Vt[d=dt*32+l31][key=16ks2+8hi+j].
    if (live) {
      __builtin_amdgcn_s_setprio(1);
      #pragma unroll
      for (int dt = 0; dt < 4; ++dt) {
        int row = dt * 32 + l31;
        int f7 = (row ^ (row >> 3)) & 7;
        #pragma unroll
        for (int ks2 = 0; ks2 < 4; ++ks2) {
          int bswz = (2 * ks2 + hi) ^ f7;
          bf16x8 vf = *(const bf16x8*)(Vc + row * 128 + bswz * 16);
          o[dt] = __builtin_amdgcn_mfma_f32_32x32x16_bf16(vf, pf[ks2], o[dt], 0, 0, 0);
        }
      }
      __builtin_amdgcn_s_setprio(0);
    }

    // ---- stage V(kt+1), then issue load_v(kt+2). Barrier at loop top
    // publishes buf^1 (lgkmcnt only; the kt+2 loads stay in flight).
    if (more) {
      __builtin_amdgcn_sched_barrier(0);
      stage_v(&Vlds[cur ^ 1][0]);
      load_v(kn);
    }
  }

  // ---- epilogue: pair-reduce denominator; per-lane scalar 1/l; store O^T.
  lrow += __shfl_xor(lrow, 32, 64);
  const float linv = 1.0f / lrow;
  float* ob = out + ((size_t)bh * Ss + qt * BM + qv) * Dd;
  #pragma unroll
  for (int dt = 0; dt < 4; ++dt)
    #pragma unroll
    for (int g = 0; g < 4; ++g) {
      float4 w;
      w.x = o[dt][g * 4 + 0] * linv;
      w.y = o[dt][g * 4 + 1] * linv;
      w.z = o[dt][g * 4 + 2] * linv;
      w.w = o[dt][g * 4 + 3] * linv;
      *(float4*)(ob + dt * 32 + g * 8 + hi4) = w;   // d = dt*32 + 8g + 4hi + c
    }
}

extern "C" void kernel_launch(void* const* d_in, const int* in_sizes, int n_in,
                              void* d_out, int out_size, void* d_ws, size_t ws_size,
                              hipStream_t stream) {
  const float* q = (const float*)d_in[0];
  const float* k = (const float*)d_in[1];
  const float* v = (const float*)d_in[2];
  float* out = (float*)d_out;
  dim3 grid(Bb * Hh * NQT);   // 512
  dim3 block(256);
  hipLaunchKernelGGL(fa_fwd_kernel, grid, block, 0, stream, q, k, v, out);
}